// Round 5
// baseline (121.505 us; speedup 1.0000x reference)
//
#include <hip/hip_runtime.h>
#include <hip/hip_bf16.h>

typedef _Float16 f16x2 __attribute__((ext_vector_type(2)));

#define BB 8
#define NN 20
#define KK 5
#define DD 230
#define NQ 200

#define NB_TR 207     // transpose 230*230
#define NB_PK 8       // pack 2048 (o,c) weight groups
#define NB_CP 180     // 46000 float4 S-copy
#define NB_CONV 1280  // 5120 1-wave conv units / 4 waves per block
#define NB_FC 300     // 2400 rows / 8 rows per block

static __device__ __forceinline__ float u2f(unsigned int u) {
    union { unsigned int u; float f; } v; v.u = u; return v.f;
}
static __device__ __forceinline__ f16x2 mkh2(float a, float b) {
    f16x2 r;
    r.x = (_Float16)a;
    r.y = (_Float16)b;
    return r;
}
static __device__ __forceinline__ unsigned int h2u(f16x2 h) {
    union { f16x2 h; unsigned int u; } v; v.h = h; return v.u;
}
static __device__ __forceinline__ f16x2 u2h(unsigned int u) {
    union { unsigned int u; f16x2 h; } v; v.u = u; return v.h;
}

// ============ k_pre: fc_w transpose + w2 f16-pair packing + S passthrough ============
__global__ void k_pre(const float* __restrict__ fc_w, float* __restrict__ Wt,
                      const float* __restrict__ w2, unsigned int* __restrict__ w2p,
                      const float* __restrict__ S, float* __restrict__ Scopy) {
    const int bid = blockIdx.x, tid = threadIdx.x;
    if (bid < NB_TR) {
        int idx = bid * 256 + tid;
        if (idx < DD * DD) {
            int i = idx / DD, j = idx % DD;
            Wt[j * DD + i] = fc_w[idx];
        }
    } else if (bid < NB_TR + NB_PK) {
        int item = (bid - NB_TR) * 256 + tid;   // o*32+c
        if (item < 2048) {
            const float* wp = w2 + (size_t)item * 5;
            float w0 = wp[0], w1 = wp[1], w2v = wp[2], w3 = wp[3], w4 = wp[4];
            unsigned int* o = w2p + (size_t)item * 6;
            o[0] = h2u(mkh2(w0, w1));
            o[1] = h2u(mkh2(w1, w2v));
            o[2] = h2u(mkh2(w2v, w3));
            o[3] = h2u(mkh2(w3, w4));
            union { float f; unsigned int u; } a, b;
            a.f = w0; b.f = w4;
            o[4] = a.u; o[5] = b.u;
        }
    } else {
        int g = (bid - NB_TR - NB_PK) * 256 + tid;
        if (g < 46000) ((float4*)Scopy)[g] = ((const float4*)S)[g];
    }
}

// ============ k_main: conv (1-wave units, dot2) + fc ============
__global__ void k_main(const float* __restrict__ S, const float* __restrict__ Q,
                       const float* __restrict__ w1, const float* __restrict__ b1,
                       const unsigned int* __restrict__ w2p, const float* __restrict__ b2,
                       const float* __restrict__ wf, float* __restrict__ sc_acc,
                       const float* __restrict__ Wt, const float* __restrict__ fc_b,
                       float* __restrict__ Sf, float* __restrict__ Qf) {
    const int bid = blockIdx.x, tid = threadIdx.x;
    if (bid < NB_CONV) {
        // ---- conv unit: vid = (img, chunk, oc-batch) ----
        const int lane = tid & 63;
        const int vid = bid * 4 + (tid >> 6);
        const int img = vid >> 5;
        const int chunk = (vid >> 3) & 3;
        const int ob = (vid & 7) * 8;
        const int d = chunk * 64 + lane;
        const bool act = d < DD;

        float in[5];
        const float* sp = S + (size_t)img * KK * DD + d;
#pragma unroll
        for (int j = 0; j < 5; j++) in[j] = act ? sp[j * DD] : 0.f;

        float acc[8][5];
#pragma unroll
        for (int oo = 0; oo < 8; oo++) {
            float bb = b2[ob + oo];
#pragma unroll
            for (int i = 0; i < 5; i++) acc[oo][i] = bb;
        }

        for (int c = 0; c < 32; c++) {
            // conv1 on the fly for channel c
            float wl[5];
#pragma unroll
            for (int t = 0; t < 5; t++) wl[t] = w1[c * 5 + t];
            float bb = b1[c];
            float x[5];
#pragma unroll
            for (int i = 0; i < 5; i++) {
                float a = bb;
#pragma unroll
                for (int t = 0; t < 5; t++) {
                    int j = i + t - 2;
                    if (j >= 0 && j < 5) a = fmaf(wl[t], in[j], a);
                }
                x[i] = fmaxf(a, 0.f);
            }
            f16x2 p01 = mkh2(x[0], x[1]);
            f16x2 p12 = mkh2(x[1], x[2]);
            f16x2 p23 = mkh2(x[2], x[3]);
            f16x2 p34 = mkh2(x[3], x[4]);

#pragma unroll
            for (int oo = 0; oo < 8; oo++) {
                const unsigned int* wp = w2p + (size_t)(((ob + oo) << 5) + c) * 6;
                f16x2 W01 = u2h(wp[0]);
                f16x2 W12 = u2h(wp[1]);
                f16x2 W23 = u2h(wp[2]);
                f16x2 W34 = u2h(wp[3]);
                float w0 = u2f(wp[4]), w4 = u2f(wp[5]);
                // i=0: w2*x0 + w3*x1 + w4*x2
                acc[oo][0] = __builtin_amdgcn_fdot2(W23, p01, acc[oo][0], false);
                acc[oo][0] = fmaf(w4, x[2], acc[oo][0]);
                // i=1: w1*x0 + w2*x1 + w3*x2 + w4*x3
                acc[oo][1] = __builtin_amdgcn_fdot2(W12, p01, acc[oo][1], false);
                acc[oo][1] = __builtin_amdgcn_fdot2(W34, p23, acc[oo][1], false);
                // i=2: full 5-tap
                acc[oo][2] = __builtin_amdgcn_fdot2(W01, p01, acc[oo][2], false);
                acc[oo][2] = __builtin_amdgcn_fdot2(W23, p23, acc[oo][2], false);
                acc[oo][2] = fmaf(w4, x[4], acc[oo][2]);
                // i=3: w0*x1 + w1*x2 + w2*x3 + w3*x4
                acc[oo][3] = __builtin_amdgcn_fdot2(W01, p12, acc[oo][3], false);
                acc[oo][3] = __builtin_amdgcn_fdot2(W23, p34, acc[oo][3], false);
                // i=4: w0*x2 + w1*x3 + w2*x4
                acc[oo][4] = fmaf(w0, x[2], acc[oo][4]);
                acc[oo][4] = __builtin_amdgcn_fdot2(W12, p34, acc[oo][4], false);
            }
        }
        // convf partial over this unit's 8 channels (stride-5 taps = positions 0..4)
        float xf = 0.f;
#pragma unroll
        for (int oo = 0; oo < 8; oo++) {
            const float* wfp = wf + (ob + oo) * 5;
#pragma unroll
            for (int t = 0; t < 5; t++)
                xf = fmaf(wfp[t], fmaxf(acc[oo][t], 0.f), xf);
        }
        if (act) atomicAdd(sc_acc + (size_t)img * DD + d, xf);
    } else {
        // ---- fc: 8 rows per block ----
        const int r0 = (bid - NB_CONV) * 8;
        const float* in;
        float* out;
        float scale;
        if (r0 < BB * NN * KK) {
            in = S + (size_t)r0 * DD;
            out = Sf + (size_t)r0 * DD;
            scale = 2.8853900817779268f;   // 2*log2(e)
        } else {
            int r = r0 - BB * NN * KK;
            in = Q + (size_t)r * DD;
            out = Qf + (size_t)r * DD;
            scale = 1.0f;
        }
        const int c = tid;
        const int cc = c < DD ? c : DD - 1;
        float a[8] = {0.f, 0.f, 0.f, 0.f, 0.f, 0.f, 0.f, 0.f};
        for (int k = 0; k < DD; k++) {
            float w = Wt[k * DD + cc];
#pragma unroll
            for (int r = 0; r < 8; r++) a[r] = fmaf(in[r * DD + k], w, a[r]);
        }
        if (c < DD) {
            float bb = fc_b[c];
#pragma unroll
            for (int r = 0; r < 8; r++) out[r * DD + c] = (a[r] + bb) * scale;
        }
    }
}

// ============ k_att: tanh-logits + softmax + einsum + weighted L2 ============
__global__ void k_att(const float* __restrict__ Sf, const float* __restrict__ Qf,
                      const float* __restrict__ S, const float* __restrict__ Q,
                      const float* __restrict__ sc_acc, const float* __restrict__ convf_b,
                      float* __restrict__ out) {
    __shared__ float Ls[NN * KK];
    const int tid = threadIdx.x, lane = tid & 63, wv = tid >> 6;
    const int bq = blockIdx.x;
    const int b = bq / NQ;
    const float LOG2E = 1.4426950408889634f;
    const float bf0 = convf_b[0];

    float qf[4];
    const float* qfp = Qf + (size_t)bq * DD;
#pragma unroll
    for (int i = 0; i < 4; i++) {
        int d = lane + 64 * i;
        qf[i] = (d < DD) ? qfp[d] : 0.f;
    }
    const float* sfb = Sf + (size_t)b * NN * KK * DD;
    for (int j = 0; j < 25; j++) {
        int idx = wv * 25 + j;   // n*5+k
        const float* sp = sfb + (size_t)idx * DD;
        float acc = 0.f;
#pragma unroll
        for (int i = 0; i < 4; i++) {
            int d = lane + 64 * i;
            float s = (d < DD) ? sp[d] : 0.f;
            float xx = s * qf[i];
            float e = __builtin_amdgcn_exp2f(xx);
            acc += 1.f - 2.f * __builtin_amdgcn_rcpf(e + 1.f);
        }
#pragma unroll
        for (int off = 32; off > 0; off >>= 1) acc += __shfl_xor(acc, off, 64);
        if (lane == 0) Ls[idx] = acc;
    }
    __syncthreads();

    float qr[4];
    const float* qp = Q + (size_t)bq * DD;
#pragma unroll
    for (int i = 0; i < 4; i++) {
        int d = lane + 64 * i;
        qr[i] = (d < DD) ? qp[d] : 0.f;
    }
    for (int jn = 0; jn < 5; jn++) {
        int n = wv * 5 + jn;
        const float* lp = Ls + n * 5;
        float v0 = lp[0], v1 = lp[1], v2 = lp[2], v3 = lp[3], v4 = lp[4];
        float m = fmaxf(fmaxf(fmaxf(v0, v1), fmaxf(v2, v3)), v4);
        float e0 = __builtin_amdgcn_exp2f((v0 - m) * LOG2E);
        float e1 = __builtin_amdgcn_exp2f((v1 - m) * LOG2E);
        float e2 = __builtin_amdgcn_exp2f((v2 - m) * LOG2E);
        float e3 = __builtin_amdgcn_exp2f((v3 - m) * LOG2E);
        float e4 = __builtin_amdgcn_exp2f((v4 - m) * LOG2E);
        float inv = __builtin_amdgcn_rcpf(e0 + e1 + e2 + e3 + e4);
        float a0 = e0 * inv, a1 = e1 * inv, a2 = e2 * inv, a3 = e3 * inv, a4 = e4 * inv;
        const float* spn = S + (size_t)(b * NN + n) * KK * DD;
        const float* scp = sc_acc + (size_t)(b * NN + n) * DD;
        float acc = 0.f;
#pragma unroll
        for (int i = 0; i < 4; i++) {
            int d = lane + 64 * i;
            if (d < DD) {
                float rep = a0 * spn[d] + a1 * spn[DD + d] + a2 * spn[2 * DD + d]
                          + a3 * spn[3 * DD + d] + a4 * spn[4 * DD + d];
                float df = rep - qr[i];
                float scw = fmaxf(scp[d] + bf0, 0.f) * 700.f;
                acc = fmaf(df * df, scw, acc);
            }
        }
#pragma unroll
        for (int off = 32; off > 0; off >>= 1) acc += __shfl_xor(acc, off, 64);
        if (lane == 0) out[(size_t)bq * NN + n] = -acc;
    }
}

extern "C" void kernel_launch(void* const* d_in, const int* in_sizes, int n_in,
                              void* d_out, int out_size, void* d_ws, size_t ws_size,
                              hipStream_t stream) {
    const float* S       = (const float*)d_in[0];
    const float* Q       = (const float*)d_in[1];
    const float* fc_w    = (const float*)d_in[2];
    const float* fc_b    = (const float*)d_in[3];
    const float* conv1_w = (const float*)d_in[4];
    const float* conv1_b = (const float*)d_in[5];
    const float* conv2_w = (const float*)d_in[6];
    const float* conv2_b = (const float*)d_in[7];
    const float* convf_w = (const float*)d_in[8];
    const float* convf_b = (const float*)d_in[9];
    float* out = (float*)d_out;

    float* ws = (float*)d_ws;
    float* Wt  = ws;                  // 52912
    float* Sf  = Wt + 52912;          // 184000
    float* Qf  = Sf + 184000;         // 368000
    float* sc  = Qf + 368000;         // 36800
    unsigned int* w2p = (unsigned int*)(sc + 36800);   // 12288 dwords

    (void)hipMemsetAsync(sc, 0, 36800 * sizeof(float), stream);
    k_pre<<<NB_TR + NB_PK + NB_CP, 256, 0, stream>>>(
        fc_w, Wt, conv2_w, w2p, S, out + (size_t)BB * NQ * NN);
    k_main<<<NB_CONV + NB_FC, 256, 0, stream>>>(
        S, Q, conv1_w, conv1_b, w2p, conv2_b, convf_w, sc, Wt, fc_b, Sf, Qf);
    k_att<<<BB * NQ, 256, 0, stream>>>(Sf, Qf, S, Q, sc, convf_b, out);
}

// Round 6
// 99.833 us; speedup vs baseline: 1.2171x; 1.2171x over previous
//
#include <hip/hip_runtime.h>
#include <hip/hip_bf16.h>

typedef _Float16 f16x2 __attribute__((ext_vector_type(2)));

#define BB 8
#define NN 20
#define KK 5
#define DD 230
#define NQ 200

#define NB_TR 207     // transpose 230*230
#define NB_PK 8       // pack 2048 (o,c) weight groups
#define NB_CP 180     // 46000 float4 S-copy
#define NB_CONV 1280  // 160 img x 4 d-chunks x 2 oo-halves
#define NB_FC 300     // 2400 rows / 8 per block

static __device__ __forceinline__ f16x2 mkh2(float a, float b) {
    f16x2 r; r.x = (_Float16)a; r.y = (_Float16)b; return r;
}
static __device__ __forceinline__ unsigned int h2u(f16x2 h) {
    union { f16x2 h; unsigned int u; } v; v.h = h; return v.u;
}
static __device__ __forceinline__ f16x2 u2h(unsigned int u) {
    union { unsigned int u; f16x2 h; } v; v.u = u; return v.h;
}

// ============ k_pre: fc_w transpose + w2 f16 pack + S passthrough ============
// pack layout: [o>>3][c][o&7][6] dwords: W01,W12,W23,W34,W4z,W0z
__global__ void k_pre(const float* __restrict__ fc_w, float* __restrict__ Wt,
                      const float* __restrict__ w2, unsigned int* __restrict__ w2p,
                      const float* __restrict__ S, float* __restrict__ Scopy) {
    const int bid = blockIdx.x, tid = threadIdx.x;
    if (bid < NB_TR) {
        int idx = bid * 256 + tid;
        if (idx < DD * DD) {
            int i = idx / DD, j = idx % DD;
            Wt[j * DD + i] = fc_w[idx];
        }
    } else if (bid < NB_TR + NB_PK) {
        int item = (bid - NB_TR) * 256 + tid;   // o*32+c
        if (item < 2048) {
            int o = item >> 5, c = item & 31;
            const float* wp = w2 + (size_t)item * 5;
            float w0 = wp[0], w1 = wp[1], w2v = wp[2], w3 = wp[3], w4 = wp[4];
            unsigned int* dst = w2p + (size_t)((((o >> 3) * 32 + c) * 8 + (o & 7)) * 6);
            dst[0] = h2u(mkh2(w0, w1));
            dst[1] = h2u(mkh2(w1, w2v));
            dst[2] = h2u(mkh2(w2v, w3));
            dst[3] = h2u(mkh2(w3, w4));
            dst[4] = h2u(mkh2(w4, 0.f));
            dst[5] = h2u(mkh2(w0, 0.f));
        }
    } else {
        int g = (bid - NB_TR - NB_PK) * 256 + tid;
        if (g < 46000) ((float4*)Scopy)[g] = ((const float4*)S)[g];
    }
}

// ============ k_main: conv (LDS f16 pairs, SGPR weights, dot2) + fc ============
__global__ __launch_bounds__(256, 5)
void k_main(const float* __restrict__ S, const float* __restrict__ Q,
            const float* __restrict__ w1, const float* __restrict__ b1,
            const unsigned int* __restrict__ w2p, const float* __restrict__ b2,
            const float* __restrict__ wf, float* __restrict__ sc_acc,
            const float* __restrict__ Wt, const float* __restrict__ fc_b,
            float* __restrict__ Sf, float* __restrict__ Qf) {
    __shared__ uint2 A64[32 * 64];          // (p01,p23) per (c,lane)
    __shared__ unsigned int C32[32 * 64];   // p4z
    const int bid = blockIdx.x, tid = threadIdx.x;
    if (bid < NB_CONV) {
        const int lane = tid & 63;
        const int wv = __builtin_amdgcn_readfirstlane(tid >> 6);  // 0..3 uniform
        const int img = bid >> 3;
        const int chunk = (bid >> 1) & 3;
        const int half = bid & 1;
        const int ob = half * 32 + wv * 8;       // uniform
        const int obq = half * 4 + wv;           // ob>>3, uniform
        const int d = chunk * 64 + lane;
        const bool act = d < DD;

        float in[5];
        const float* sp = S + (size_t)img * KK * DD + d;
#pragma unroll
        for (int j = 0; j < 5; j++) in[j] = act ? sp[j * DD] : 0.f;

        // conv1: this wave computes channels c = wv*8 .. wv*8+7, packs to f16 pairs
#pragma unroll
        for (int ci = 0; ci < 8; ci++) {
            int c = wv * 8 + ci;
            float wl[5];
#pragma unroll
            for (int t = 0; t < 5; t++) wl[t] = w1[c * 5 + t];
            float bb = b1[c];
            float x[5];
#pragma unroll
            for (int i = 0; i < 5; i++) {
                float a = bb;
#pragma unroll
                for (int t = 0; t < 5; t++) {
                    int j = i + t - 2;
                    if (j >= 0 && j < 5) a = fmaf(wl[t], in[j], a);
                }
                x[i] = fmaxf(a, 0.f);
            }
            A64[c * 64 + lane] = make_uint2(h2u(mkh2(x[0], x[1])), h2u(mkh2(x[2], x[3])));
            C32[c * 64 + lane] = h2u(mkh2(x[4], 0.f));
        }
        __syncthreads();

        // conv2: 8 output channels per wave, SGPR weights, 11 dot2 per (oo,c)
        float acc[8][5];
#pragma unroll
        for (int oo = 0; oo < 8; oo++) {
            float bb = b2[ob + oo];
#pragma unroll
            for (int i = 0; i < 5; i++) acc[oo][i] = bb;
        }
        for (int c = 0; c < 32; c++) {
            uint2 ab = A64[c * 64 + lane];
            unsigned int p01 = ab.x, p23 = ab.y;
            unsigned int p4z = C32[c * 64 + lane];
            unsigned int p12 = (p01 >> 16) | (p23 << 16);
            unsigned int p34 = (p23 >> 16) | (p4z << 16);
            unsigned int p22 = (p23 & 0xffffu); p22 |= p22 << 16;
            unsigned int p44 = (p4z & 0xffffu); p44 |= p44 << 16;
            f16x2 q01 = u2h(p01), q23 = u2h(p23), q12 = u2h(p12);
            f16x2 q34 = u2h(p34), q22 = u2h(p22), q44 = u2h(p44);
            const unsigned int* wcb = w2p + (size_t)(((obq * 32 + c) * 8) * 6);
#pragma unroll
            for (int oo = 0; oo < 8; oo++) {
                f16x2 W01 = u2h(wcb[oo * 6 + 0]);
                f16x2 W12 = u2h(wcb[oo * 6 + 1]);
                f16x2 W23 = u2h(wcb[oo * 6 + 2]);
                f16x2 W34 = u2h(wcb[oo * 6 + 3]);
                f16x2 W4z = u2h(wcb[oo * 6 + 4]);
                f16x2 W0z = u2h(wcb[oo * 6 + 5]);
                acc[oo][0] = __builtin_amdgcn_fdot2(W23, q01, acc[oo][0], false);
                acc[oo][0] = __builtin_amdgcn_fdot2(W4z, q22, acc[oo][0], false);
                acc[oo][1] = __builtin_amdgcn_fdot2(W12, q01, acc[oo][1], false);
                acc[oo][1] = __builtin_amdgcn_fdot2(W34, q23, acc[oo][1], false);
                acc[oo][2] = __builtin_amdgcn_fdot2(W01, q01, acc[oo][2], false);
                acc[oo][2] = __builtin_amdgcn_fdot2(W23, q23, acc[oo][2], false);
                acc[oo][2] = __builtin_amdgcn_fdot2(W4z, q44, acc[oo][2], false);
                acc[oo][3] = __builtin_amdgcn_fdot2(W01, q12, acc[oo][3], false);
                acc[oo][3] = __builtin_amdgcn_fdot2(W23, q34, acc[oo][3], false);
                acc[oo][4] = __builtin_amdgcn_fdot2(W0z, q22, acc[oo][4], false);
                acc[oo][4] = __builtin_amdgcn_fdot2(W12, q34, acc[oo][4], false);
            }
        }
        // convf partial (stride-5 taps = positions 0..4) + atomic combine
        float xf = 0.f;
#pragma unroll
        for (int oo = 0; oo < 8; oo++) {
            const float* wfp = wf + (ob + oo) * 5;
#pragma unroll
            for (int t = 0; t < 5; t++)
                xf = fmaf(wfp[t], fmaxf(acc[oo][t], 0.f), xf);
        }
        if (act) atomicAdd(sc_acc + (size_t)img * DD + d, xf);
    } else {
        // ---- fc: 8 rows per block ----
        const int r0 = (bid - NB_CONV) * 8;
        const float* in;
        float* out;
        float scale;
        if (r0 < BB * NN * KK) {
            in = S + (size_t)r0 * DD;
            out = Sf + (size_t)r0 * DD;
            scale = 2.8853900817779268f;   // 2*log2(e)
        } else {
            int r = r0 - BB * NN * KK;
            in = Q + (size_t)r * DD;
            out = Qf + (size_t)r * DD;
            scale = 1.0f;
        }
        const int c = tid;
        const int cc = c < DD ? c : DD - 1;
        float a[8] = {0.f, 0.f, 0.f, 0.f, 0.f, 0.f, 0.f, 0.f};
        for (int k = 0; k < DD; k++) {
            float w = Wt[k * DD + cc];
#pragma unroll
            for (int r = 0; r < 8; r++) a[r] = fmaf(in[r * DD + k], w, a[r]);
        }
        if (c < DD) {
            float bb = fc_b[c];
#pragma unroll
            for (int r = 0; r < 8; r++) out[r * DD + c] = (a[r] + bb) * scale;
        }
    }
}

// ============ k_att: Sf tile in LDS; tanh-logits + softmax + einsum + L2 ============
// block = (b, n-quarter of 5 n's, q-group of 8). 800 blocks x 256.
__global__ void k_att(const float* __restrict__ Sf, const float* __restrict__ Qf,
                      const float* __restrict__ S, const float* __restrict__ Q,
                      const float* __restrict__ sc_acc, const float* __restrict__ convf_b,
                      float* __restrict__ out) {
    __shared__ float Sft[25][232];
    __shared__ float Ls[8][25];
    const int bid = blockIdx.x, tid = threadIdx.x;
    const int lane = tid & 63, wv = tid >> 6;
    const int qg = bid % 25;
    const int nq = (bid / 25) & 3;
    const int b  = bid / 100;
    const int q0 = qg * 8, n0 = nq * 5;
    const float LOG2E = 1.4426950408889634f;
    const float bf0 = convf_b[0];

    // stage Sf tile: rows b*100 + n0*5 .. +25
    const float* sfb = Sf + ((size_t)b * 100 + n0 * 5) * DD;
    for (int e = tid; e < 25 * DD; e += 256) {
        int rr = e / DD, cc = e - rr * DD;
        Sft[rr][cc] = sfb[rr * DD + cc];
    }
    __syncthreads();

    // part 1: L[q][idx] = sum_d tanh(Sf*Qf); wave wv handles q = q0+wv*2+{0,1}
#pragma unroll
    for (int ql = 0; ql < 2; ql++) {
        const int q = q0 + wv * 2 + ql;
        float qf[4];
        const float* qfp = Qf + ((size_t)b * NQ + q) * DD;
#pragma unroll
        for (int i = 0; i < 4; i++) {
            int d = lane + 64 * i;
            qf[i] = (d < DD) ? qfp[d] : 0.f;
        }
        for (int idx = 0; idx < 25; idx++) {
            float acc = 0.f;
#pragma unroll
            for (int i = 0; i < 4; i++) {
                int d = lane + 64 * i;
                float s = (d < DD) ? Sft[idx][d] : 0.f;
                float xx = s * qf[i];
                float e = __builtin_amdgcn_exp2f(xx);
                acc += 1.f - 2.f * __builtin_amdgcn_rcpf(e + 1.f);
            }
#pragma unroll
            for (int off = 32; off > 0; off >>= 1) acc += __shfl_xor(acc, off, 64);
            if (lane == 0) Ls[wv * 2 + ql][idx] = acc;
        }
    }
    __syncthreads();

    // part 2: softmax(K) + einsum + weighted L2 for this block's 5 n's
#pragma unroll
    for (int ql = 0; ql < 2; ql++) {
        const int q = q0 + wv * 2 + ql;
        float qr[4];
        const float* qp = Q + ((size_t)b * NQ + q) * DD;
#pragma unroll
        for (int i = 0; i < 4; i++) {
            int d = lane + 64 * i;
            qr[i] = (d < DD) ? qp[d] : 0.f;
        }
        for (int nl = 0; nl < 5; nl++) {
            const float* lp = Ls[wv * 2 + ql] + nl * 5;
            float v0 = lp[0], v1 = lp[1], v2 = lp[2], v3 = lp[3], v4 = lp[4];
            float m = fmaxf(fmaxf(fmaxf(v0, v1), fmaxf(v2, v3)), v4);
            float e0 = __builtin_amdgcn_exp2f((v0 - m) * LOG2E);
            float e1 = __builtin_amdgcn_exp2f((v1 - m) * LOG2E);
            float e2 = __builtin_amdgcn_exp2f((v2 - m) * LOG2E);
            float e3 = __builtin_amdgcn_exp2f((v3 - m) * LOG2E);
            float e4 = __builtin_amdgcn_exp2f((v4 - m) * LOG2E);
            float inv = __builtin_amdgcn_rcpf(e0 + e1 + e2 + e3 + e4);
            float a0 = e0 * inv, a1 = e1 * inv, a2 = e2 * inv, a3 = e3 * inv, a4 = e4 * inv;
            const int n = n0 + nl;
            const float* spn = S + (size_t)(b * NN + n) * KK * DD;
            const float* scp = sc_acc + (size_t)(b * NN + n) * DD;
            float acc = 0.f;
#pragma unroll
            for (int i = 0; i < 4; i++) {
                int d = lane + 64 * i;
                if (d < DD) {
                    float rep = a0 * spn[d] + a1 * spn[DD + d] + a2 * spn[2 * DD + d]
                              + a3 * spn[3 * DD + d] + a4 * spn[4 * DD + d];
                    float df = rep - qr[i];
                    float scw = fmaxf(scp[d] + bf0, 0.f) * 700.f;
                    acc = fmaf(df * df, scw, acc);
                }
            }
#pragma unroll
            for (int off = 32; off > 0; off >>= 1) acc += __shfl_xor(acc, off, 64);
            if (lane == 0) out[((size_t)b * NQ + q) * NN + n] = -acc;
        }
    }
}

extern "C" void kernel_launch(void* const* d_in, const int* in_sizes, int n_in,
                              void* d_out, int out_size, void* d_ws, size_t ws_size,
                              hipStream_t stream) {
    const float* S       = (const float*)d_in[0];
    const float* Q       = (const float*)d_in[1];
    const float* fc_w    = (const float*)d_in[2];
    const float* fc_b    = (const float*)d_in[3];
    const float* conv1_w = (const float*)d_in[4];
    const float* conv1_b = (const float*)d_in[5];
    const float* conv2_w = (const float*)d_in[6];
    const float* conv2_b = (const float*)d_in[7];
    const float* convf_w = (const float*)d_in[8];
    const float* convf_b = (const float*)d_in[9];
    float* out = (float*)d_out;

    float* ws = (float*)d_ws;
    float* Wt  = ws;                  // 52912
    float* Sf  = Wt + 52912;          // 184000
    float* Qf  = Sf + 184000;         // 368000
    float* sc  = Qf + 368000;         // 36800
    unsigned int* w2p = (unsigned int*)(sc + 36800);   // 12288 dwords

    (void)hipMemsetAsync(sc, 0, 36800 * sizeof(float), stream);
    k_pre<<<NB_TR + NB_PK + NB_CP, 256, 0, stream>>>(
        fc_w, Wt, conv2_w, w2p, S, out + (size_t)BB * NQ * NN);
    k_main<<<NB_CONV + NB_FC, 256, 0, stream>>>(
        S, Q, conv1_w, conv1_b, w2p, conv2_b, convf_w, sc, Wt, fc_b, Sf, Qf);
    k_att<<<BB * NQ / 2, 256, 0, stream>>>(Sf, Qf, S, Q, sc, convf_b, out);
}

// Round 7
// 92.254 us; speedup vs baseline: 1.3171x; 1.0822x over previous
//
#include <hip/hip_runtime.h>
#include <hip/hip_bf16.h>

typedef _Float16 f16x2 __attribute__((ext_vector_type(2)));

#define BB 8
#define NN 20
#define KK 5
#define DD 230
#define NQ 200

#define NB_TR 207     // transpose 230*230
#define NB_PK 8       // pack 2048 (o,c) weight groups
#define NB_CP 180     // 46000 float4 S-copy
#define NB_FC 300     // 2400 rows / 8 per block (FIRST in grid: overlaps conv)
#define NB_CONV 1280  // 160 img x 4 d-chunks x 2 oo-halves

static __device__ __forceinline__ f16x2 mkh2(float a, float b) {
    f16x2 r; r.x = (_Float16)a; r.y = (_Float16)b; return r;
}
static __device__ __forceinline__ unsigned int h2u(f16x2 h) {
    union { f16x2 h; unsigned int u; } v; v.h = h; return v.u;
}
static __device__ __forceinline__ f16x2 u2h(unsigned int u) {
    union { unsigned int u; f16x2 h; } v; v.u = u; return v.h;
}

// ============ k_pre: fc_w transpose + w2 f16 SoA pack + S passthrough ============
// pack layout idx = (half*32 + c)*32 + oo_local
//   w2pA[idx] = uint4 {W01,W12,W23,W34}; w2pB[idx] = uint2 {W4z,W0z}
__global__ void k_pre(const float* __restrict__ fc_w, float* __restrict__ Wt,
                      const float* __restrict__ w2,
                      uint4* __restrict__ w2pA, uint2* __restrict__ w2pB,
                      const float* __restrict__ S, float* __restrict__ Scopy) {
    const int bid = blockIdx.x, tid = threadIdx.x;
    if (bid < NB_TR) {
        int idx = bid * 256 + tid;
        if (idx < DD * DD) {
            int i = idx / DD, j = idx % DD;
            Wt[j * DD + i] = fc_w[idx];
        }
    } else if (bid < NB_TR + NB_PK) {
        int item = (bid - NB_TR) * 256 + tid;   // o*32+c
        if (item < 2048) {
            int o = item >> 5, c = item & 31;
            const float* wp = w2 + (size_t)item * 5;
            float w0 = wp[0], w1 = wp[1], w2v = wp[2], w3 = wp[3], w4 = wp[4];
            int idx = ((o >> 5) * 32 + c) * 32 + (o & 31);
            w2pA[idx] = make_uint4(h2u(mkh2(w0, w1)), h2u(mkh2(w1, w2v)),
                                   h2u(mkh2(w2v, w3)), h2u(mkh2(w3, w4)));
            w2pB[idx] = make_uint2(h2u(mkh2(w4, 0.f)), h2u(mkh2(w0, 0.f)));
        }
    } else {
        int g = (bid - NB_TR - NB_PK) * 256 + tid;
        if (g < 46000) ((float4*)Scopy)[g] = ((const float4*)S)[g];
    }
}

// ============ k_main: fc (blocks 0..299) + conv (blocks 300..1579) ============
__global__ __launch_bounds__(256, 3)
void k_main(const float* __restrict__ S, const float* __restrict__ Q,
            const float* __restrict__ w1, const float* __restrict__ b1,
            const uint4* __restrict__ w2pA, const uint2* __restrict__ w2pB,
            const float* __restrict__ b2,
            const float* __restrict__ wf, float* __restrict__ sc_acc,
            const float* __restrict__ Wt, const float* __restrict__ fc_b,
            float* __restrict__ Sf, float* __restrict__ Qf) {
    __shared__ uint2 A64[32 * 64];          // x1 (p01,p23) per (c,lane)   16 KB
    __shared__ unsigned int C32[32 * 64];   // x1 p4z                       8 KB
    __shared__ uint4 Wa[32 * 32];           // weights W01..W34 [c][oo]    16 KB
    __shared__ uint2 Wb[32 * 32];           // weights W4z,W0z  [c][oo]     8 KB
    const int bid = blockIdx.x, tid = threadIdx.x;

    if (bid < NB_FC) {
        // ---- fc: 8 rows per block ----
        const int r0 = bid * 8;
        const float* in;
        float* out;
        float scale;
        if (r0 < BB * NN * KK) {
            in = S + (size_t)r0 * DD;
            out = Sf + (size_t)r0 * DD;
            scale = 2.8853900817779268f;   // 2*log2(e)
        } else {
            int r = r0 - BB * NN * KK;
            in = Q + (size_t)r * DD;
            out = Qf + (size_t)r * DD;
            scale = 1.0f;
        }
        const int c = tid;
        const int cc = c < DD ? c : DD - 1;
        float a[8] = {0.f, 0.f, 0.f, 0.f, 0.f, 0.f, 0.f, 0.f};
        for (int k = 0; k < DD; k++) {
            float w = Wt[k * DD + cc];
#pragma unroll
            for (int r = 0; r < 8; r++) a[r] = fmaf(in[r * DD + k], w, a[r]);
        }
        if (c < DD) {
            float bb = fc_b[c];
#pragma unroll
            for (int r = 0; r < 8; r++) out[r * DD + c] = (a[r] + bb) * scale;
        }
        return;
    }

    // ---- conv ----
    const int bid2 = bid - NB_FC;
    const int lane = tid & 63;
    const int wv = __builtin_amdgcn_readfirstlane(tid >> 6);  // 0..3 uniform
    const int img = bid2 >> 3;
    const int chunk = (bid2 >> 1) & 3;
    const int half = bid2 & 1;
    const int ob = half * 32 + wv * 8;       // uniform global oc base
    const int wv8 = wv * 8;                  // uniform oc base within half
    const int d = chunk * 64 + lane;
    const bool act = d < DD;

    // stage this half's weights into LDS (issued early, hides under conv1)
    {
        const uint4* ga = w2pA + (half << 10);
        const uint2* gb = w2pB + (half << 10);
#pragma unroll
        for (int e = 0; e < 4; e++) {
            Wa[tid + 256 * e] = ga[tid + 256 * e];
            Wb[tid + 256 * e] = gb[tid + 256 * e];
        }
    }

    // conv1: this wave computes channels c = wv*8 .. wv*8+7, packs to f16 pairs
    float in[5];
    const float* sp = S + (size_t)img * KK * DD + d;
#pragma unroll
    for (int j = 0; j < 5; j++) in[j] = act ? sp[j * DD] : 0.f;
#pragma unroll
    for (int ci = 0; ci < 8; ci++) {
        int c = wv * 8 + ci;
        float wl[5];
#pragma unroll
        for (int t = 0; t < 5; t++) wl[t] = w1[c * 5 + t];
        float bb = b1[c];
        float x[5];
#pragma unroll
        for (int i = 0; i < 5; i++) {
            float a = bb;
#pragma unroll
            for (int t = 0; t < 5; t++) {
                int j = i + t - 2;
                if (j >= 0 && j < 5) a = fmaf(wl[t], in[j], a);
            }
            x[i] = fmaxf(a, 0.f);
        }
        A64[c * 64 + lane] = make_uint2(h2u(mkh2(x[0], x[1])), h2u(mkh2(x[2], x[3])));
        C32[c * 64 + lane] = h2u(mkh2(x[4], 0.f));
    }
    __syncthreads();

    // conv2: 8 oc per wave; weights broadcast from LDS; 11 dot2 per (oo,c)
    float acc[8][5];
#pragma unroll
    for (int oo = 0; oo < 8; oo++) {
        float bb = b2[ob + oo];
#pragma unroll
        for (int i = 0; i < 5; i++) acc[oo][i] = bb;
    }
    for (int c = 0; c < 32; c++) {
        uint2 ab = A64[c * 64 + lane];
        unsigned int p01 = ab.x, p23 = ab.y;
        unsigned int p4z = C32[c * 64 + lane];
        unsigned int p12 = (p01 >> 16) | (p23 << 16);
        unsigned int p34 = (p23 >> 16) | (p4z << 16);
        unsigned int p22 = (p23 & 0xffffu); p22 |= p22 << 16;
        unsigned int p44 = (p4z & 0xffffu); p44 |= p44 << 16;
        f16x2 q01 = u2h(p01), q23 = u2h(p23), q12 = u2h(p12);
        f16x2 q34 = u2h(p34), q22 = u2h(p22), q44 = u2h(p44);
#pragma unroll
        for (int oo = 0; oo < 8; oo++) {
            uint4 WA = Wa[c * 32 + wv8 + oo];
            uint2 WB = Wb[c * 32 + wv8 + oo];
            f16x2 W01 = u2h(WA.x), W12 = u2h(WA.y);
            f16x2 W23 = u2h(WA.z), W34 = u2h(WA.w);
            f16x2 W4z = u2h(WB.x), W0z = u2h(WB.y);
            acc[oo][0] = __builtin_amdgcn_fdot2(W23, q01, acc[oo][0], false);
            acc[oo][0] = __builtin_amdgcn_fdot2(W4z, q22, acc[oo][0], false);
            acc[oo][1] = __builtin_amdgcn_fdot2(W12, q01, acc[oo][1], false);
            acc[oo][1] = __builtin_amdgcn_fdot2(W34, q23, acc[oo][1], false);
            acc[oo][2] = __builtin_amdgcn_fdot2(W01, q01, acc[oo][2], false);
            acc[oo][2] = __builtin_amdgcn_fdot2(W23, q23, acc[oo][2], false);
            acc[oo][2] = __builtin_amdgcn_fdot2(W4z, q44, acc[oo][2], false);
            acc[oo][3] = __builtin_amdgcn_fdot2(W01, q12, acc[oo][3], false);
            acc[oo][3] = __builtin_amdgcn_fdot2(W23, q34, acc[oo][3], false);
            acc[oo][4] = __builtin_amdgcn_fdot2(W0z, q22, acc[oo][4], false);
            acc[oo][4] = __builtin_amdgcn_fdot2(W12, q34, acc[oo][4], false);
        }
    }
    // convf partial (stride-5 taps = positions 0..4) + atomic combine
    float xf = 0.f;
#pragma unroll
    for (int oo = 0; oo < 8; oo++) {
        const float* wfp = wf + (ob + oo) * 5;
#pragma unroll
        for (int t = 0; t < 5; t++)
            xf = fmaf(wfp[t], fmaxf(acc[oo][t], 0.f), xf);
    }
    if (act) atomicAdd(sc_acc + (size_t)img * DD + d, xf);
}

// ============ k_att: Sf tile in LDS; tanh-logits + softmax + einsum + L2 ============
__global__ void k_att(const float* __restrict__ Sf, const float* __restrict__ Qf,
                      const float* __restrict__ S, const float* __restrict__ Q,
                      const float* __restrict__ sc_acc, const float* __restrict__ convf_b,
                      float* __restrict__ out) {
    __shared__ float Sft[25][232];
    __shared__ float Ls[8][25];
    const int bid = blockIdx.x, tid = threadIdx.x;
    const int lane = tid & 63, wv = tid >> 6;
    const int qg = bid % 25;
    const int nq = (bid / 25) & 3;
    const int b  = bid / 100;
    const int q0 = qg * 8, n0 = nq * 5;
    const float LOG2E = 1.4426950408889634f;
    const float bf0 = convf_b[0];

    const float* sfb = Sf + ((size_t)b * 100 + n0 * 5) * DD;
    for (int e = tid; e < 25 * DD; e += 256) {
        int rr = e / DD, cc = e - rr * DD;
        Sft[rr][cc] = sfb[rr * DD + cc];
    }
    __syncthreads();

#pragma unroll
    for (int ql = 0; ql < 2; ql++) {
        const int q = q0 + wv * 2 + ql;
        float qf[4];
        const float* qfp = Qf + ((size_t)b * NQ + q) * DD;
#pragma unroll
        for (int i = 0; i < 4; i++) {
            int d = lane + 64 * i;
            qf[i] = (d < DD) ? qfp[d] : 0.f;
        }
        for (int idx = 0; idx < 25; idx++) {
            float acc = 0.f;
#pragma unroll
            for (int i = 0; i < 4; i++) {
                int d = lane + 64 * i;
                float s = (d < DD) ? Sft[idx][d] : 0.f;
                float xx = s * qf[i];
                float e = __builtin_amdgcn_exp2f(xx);
                acc += 1.f - 2.f * __builtin_amdgcn_rcpf(e + 1.f);
            }
#pragma unroll
            for (int off = 32; off > 0; off >>= 1) acc += __shfl_xor(acc, off, 64);
            if (lane == 0) Ls[wv * 2 + ql][idx] = acc;
        }
    }
    __syncthreads();

#pragma unroll
    for (int ql = 0; ql < 2; ql++) {
        const int q = q0 + wv * 2 + ql;
        float qr[4];
        const float* qp = Q + ((size_t)b * NQ + q) * DD;
#pragma unroll
        for (int i = 0; i < 4; i++) {
            int d = lane + 64 * i;
            qr[i] = (d < DD) ? qp[d] : 0.f;
        }
        for (int nl = 0; nl < 5; nl++) {
            const float* lp = Ls[wv * 2 + ql] + nl * 5;
            float v0 = lp[0], v1 = lp[1], v2 = lp[2], v3 = lp[3], v4 = lp[4];
            float m = fmaxf(fmaxf(fmaxf(v0, v1), fmaxf(v2, v3)), v4);
            float e0 = __builtin_amdgcn_exp2f((v0 - m) * LOG2E);
            float e1 = __builtin_amdgcn_exp2f((v1 - m) * LOG2E);
            float e2 = __builtin_amdgcn_exp2f((v2 - m) * LOG2E);
            float e3 = __builtin_amdgcn_exp2f((v3 - m) * LOG2E);
            float e4 = __builtin_amdgcn_exp2f((v4 - m) * LOG2E);
            float inv = __builtin_amdgcn_rcpf(e0 + e1 + e2 + e3 + e4);
            float a0 = e0 * inv, a1 = e1 * inv, a2 = e2 * inv, a3 = e3 * inv, a4 = e4 * inv;
            const int n = n0 + nl;
            const float* spn = S + (size_t)(b * NN + n) * KK * DD;
            const float* scp = sc_acc + (size_t)(b * NN + n) * DD;
            float acc = 0.f;
#pragma unroll
            for (int i = 0; i < 4; i++) {
                int d = lane + 64 * i;
                if (d < DD) {
                    float rep = a0 * spn[d] + a1 * spn[DD + d] + a2 * spn[2 * DD + d]
                              + a3 * spn[3 * DD + d] + a4 * spn[4 * DD + d];
                    float df = rep - qr[i];
                    float scw = fmaxf(scp[d] + bf0, 0.f) * 700.f;
                    acc = fmaf(df * df, scw, acc);
                }
            }
#pragma unroll
            for (int off = 32; off > 0; off >>= 1) acc += __shfl_xor(acc, off, 64);
            if (lane == 0) out[((size_t)b * NQ + q) * NN + n] = -acc;
        }
    }
}

extern "C" void kernel_launch(void* const* d_in, const int* in_sizes, int n_in,
                              void* d_out, int out_size, void* d_ws, size_t ws_size,
                              hipStream_t stream) {
    const float* S       = (const float*)d_in[0];
    const float* Q       = (const float*)d_in[1];
    const float* fc_w    = (const float*)d_in[2];
    const float* fc_b    = (const float*)d_in[3];
    const float* conv1_w = (const float*)d_in[4];
    const float* conv1_b = (const float*)d_in[5];
    const float* conv2_w = (const float*)d_in[6];
    const float* conv2_b = (const float*)d_in[7];
    const float* convf_w = (const float*)d_in[8];
    const float* convf_b = (const float*)d_in[9];
    float* out = (float*)d_out;

    float* ws = (float*)d_ws;
    float* Wt  = ws;                                    // 52912 dwords
    float* Sf  = Wt + 52912;                            // 184000
    float* Qf  = Sf + 184000;                           // 368000
    float* sc  = Qf + 368000;                           // 36800
    uint4* w2pA = (uint4*)(sc + 36800);                 // 2048 uint4 (8192 dw)
    uint2* w2pB = (uint2*)((float*)w2pA + 8192);        // 2048 uint2 (4096 dw)

    (void)hipMemsetAsync(sc, 0, 36800 * sizeof(float), stream);
    k_pre<<<NB_TR + NB_PK + NB_CP, 256, 0, stream>>>(
        fc_w, Wt, conv2_w, w2pA, w2pB, S, out + (size_t)BB * NQ * NN);
    k_main<<<NB_FC + NB_CONV, 256, 0, stream>>>(
        S, Q, conv1_w, conv1_b, w2pA, w2pB, conv2_b, convf_w, sc, Wt, fc_b, Sf, Qf);
    k_att<<<BB * NQ / 2, 256, 0, stream>>>(Sf, Qf, S, Q, sc, convf_b, out);
}

// Round 8
// 92.044 us; speedup vs baseline: 1.3201x; 1.0023x over previous
//
#include <hip/hip_runtime.h>
#include <hip/hip_bf16.h>

typedef _Float16 f16x2 __attribute__((ext_vector_type(2)));

#define BB 8
#define NN 20
#define KK 5
#define DD 230
#define NQ 200

#define NB_TR 207     // transpose 230*230
#define NB_PK 8       // pack 2048 (o,c) weight groups
#define NB_CP 180     // 46000 float4 S-copy
#define NB_FC 300     // 2400 rows / 8 per block (first: overlaps conv)
#define NB_CONV 1280  // 160 img x 4 d-chunks x 2 oc-halves
#define NB_ATT 800    // 8 b x 4 n-quarters x 25 q-groups

static __device__ __forceinline__ f16x2 mkh2(float a, float b) {
    f16x2 r; r.x = (_Float16)a; r.y = (_Float16)b; return r;
}
static __device__ __forceinline__ unsigned int h2u(f16x2 h) {
    union { f16x2 h; unsigned int u; } v; v.h = h; return v.u;
}
static __device__ __forceinline__ f16x2 u2h(unsigned int u) {
    union { unsigned int u; f16x2 h; } v; v.u = u; return v.h;
}

// ============ k_pre: fc_w transpose + w2 f16 SoA pack + S passthrough ============
// pack idx = (half*32 + c)*32 + oc_local
__global__ void k_pre(const float* __restrict__ fc_w, float* __restrict__ Wt,
                      const float* __restrict__ w2,
                      uint4* __restrict__ w2pA, uint2* __restrict__ w2pB,
                      const float* __restrict__ S, float* __restrict__ Scopy) {
    const int bid = blockIdx.x, tid = threadIdx.x;
    if (bid < NB_TR) {
        int idx = bid * 256 + tid;
        if (idx < DD * DD) {
            int i = idx / DD, j = idx % DD;
            Wt[j * DD + i] = fc_w[idx];
        }
    } else if (bid < NB_TR + NB_PK) {
        int item = (bid - NB_TR) * 256 + tid;   // o*32+c
        if (item < 2048) {
            int o = item >> 5, c = item & 31;
            const float* wp = w2 + (size_t)item * 5;
            float w0 = wp[0], w1 = wp[1], w2v = wp[2], w3 = wp[3], w4 = wp[4];
            int idx = ((o >> 5) * 32 + c) * 32 + (o & 31);
            w2pA[idx] = make_uint4(h2u(mkh2(w0, w1)), h2u(mkh2(w1, w2v)),
                                   h2u(mkh2(w2v, w3)), h2u(mkh2(w3, w4)));
            w2pB[idx] = make_uint2(h2u(mkh2(w4, 0.f)), h2u(mkh2(w0, 0.f)));
        }
    } else {
        int g = (bid - NB_TR - NB_PK) * 256 + tid;
        if (g < 46000) ((float4*)Scopy)[g] = ((const float4*)S)[g];
    }
}

// ============ k_main: fc (blocks 0..299) + conv (blocks 300..1579) ============
// conv: LDS holds only the half's weights (24 KB); x1 computed in-wave.
__global__ __launch_bounds__(256, 4)
void k_main(const float* __restrict__ S, const float* __restrict__ Q,
            const float* __restrict__ w1, const float* __restrict__ b1,
            const uint4* __restrict__ w2pA, const uint2* __restrict__ w2pB,
            const float* __restrict__ b2,
            const float* __restrict__ wf, float* __restrict__ sc_acc,
            const float* __restrict__ Wt, const float* __restrict__ fc_b,
            float* __restrict__ Sf, float* __restrict__ Qf) {
    __shared__ uint4 Wa[32 * 32];   // [c][oc_local] W01..W34   16 KB
    __shared__ uint2 Wb[32 * 32];   // [c][oc_local] W4z,W0z     8 KB
    const int bid = blockIdx.x, tid = threadIdx.x;

    if (bid < NB_FC) {
        // ---- fc: 8 rows per block ----
        const int r0 = bid * 8;
        const float* in;
        float* out;
        float scale;
        if (r0 < BB * NN * KK) {
            in = S + (size_t)r0 * DD;
            out = Sf + (size_t)r0 * DD;
            scale = 2.8853900817779268f;   // 2*log2(e)
        } else {
            int r = r0 - BB * NN * KK;
            in = Q + (size_t)r * DD;
            out = Qf + (size_t)r * DD;
            scale = 1.0f;
        }
        const int c = tid;
        const int cc = c < DD ? c : DD - 1;
        float a[8] = {0.f, 0.f, 0.f, 0.f, 0.f, 0.f, 0.f, 0.f};
        for (int k = 0; k < DD; k++) {
            float w = Wt[k * DD + cc];
#pragma unroll
            for (int r = 0; r < 8; r++) a[r] = fmaf(in[r * DD + k], w, a[r]);
        }
        if (c < DD) {
            float bb = fc_b[c];
#pragma unroll
            for (int r = 0; r < 8; r++) out[r * DD + c] = (a[r] + bb) * scale;
        }
        return;
    }

    // ---- conv ----
    const int bid2 = bid - NB_FC;
    const int lane = tid & 63;
    const int wv = __builtin_amdgcn_readfirstlane(tid >> 6);  // 0..3 uniform
    const int img = bid2 >> 3;
    const int chunk = (bid2 >> 1) & 3;
    const int half = bid2 & 1;
    const int ob = half * 32 + wv * 8;   // uniform global oc base
    const int wv8 = wv * 8;              // uniform oc base within half
    const int d = chunk * 64 + lane;
    const bool act = d < DD;

    // stage this half's weights into LDS
    {
        const uint4* ga = w2pA + (half << 10);
        const uint2* gb = w2pB + (half << 10);
#pragma unroll
        for (int e = 0; e < 4; e++) {
            Wa[tid + 256 * e] = ga[tid + 256 * e];
            Wb[tid + 256 * e] = gb[tid + 256 * e];
        }
    }

    // input column
    float in[5];
    const float* sp = S + (size_t)img * KK * DD + d;
#pragma unroll
    for (int j = 0; j < 5; j++) in[j] = act ? sp[j * DD] : 0.f;

    float acc[8][5];
#pragma unroll
    for (int oo = 0; oo < 8; oo++) {
        float bb = b2[ob + oo];
#pragma unroll
        for (int i = 0; i < 5; i++) acc[oo][i] = bb;
    }
    __syncthreads();

    for (int c = 0; c < 32; c++) {
        // conv1 on the fly (wave-redundant, register-resident)
        float wl[5];
#pragma unroll
        for (int t = 0; t < 5; t++) wl[t] = w1[c * 5 + t];
        float bb = b1[c];
        float x[5];
#pragma unroll
        for (int i = 0; i < 5; i++) {
            float a = bb;
#pragma unroll
            for (int t = 0; t < 5; t++) {
                int j = i + t - 2;
                if (j >= 0 && j < 5) a = fmaf(wl[t], in[j], a);
            }
            x[i] = fmaxf(a, 0.f);
        }
        unsigned int p01 = h2u(mkh2(x[0], x[1]));
        unsigned int p23 = h2u(mkh2(x[2], x[3]));
        unsigned int p4z = h2u(mkh2(x[4], 0.f));
        unsigned int p12 = (p01 >> 16) | (p23 << 16);
        unsigned int p34 = (p23 >> 16) | (p4z << 16);
        f16x2 q01 = u2h(p01), q23 = u2h(p23), q12 = u2h(p12), q34 = u2h(p34);
        f16x2 q22 = mkh2(x[2], x[2]), q44 = mkh2(x[4], x[4]);
#pragma unroll
        for (int oo = 0; oo < 8; oo++) {
            uint4 WA = Wa[c * 32 + wv8 + oo];
            uint2 WB = Wb[c * 32 + wv8 + oo];
            f16x2 W01 = u2h(WA.x), W12 = u2h(WA.y);
            f16x2 W23 = u2h(WA.z), W34 = u2h(WA.w);
            f16x2 W4z = u2h(WB.x), W0z = u2h(WB.y);
            acc[oo][0] = __builtin_amdgcn_fdot2(W23, q01, acc[oo][0], false);
            acc[oo][0] = __builtin_amdgcn_fdot2(W4z, q22, acc[oo][0], false);
            acc[oo][1] = __builtin_amdgcn_fdot2(W12, q01, acc[oo][1], false);
            acc[oo][1] = __builtin_amdgcn_fdot2(W34, q23, acc[oo][1], false);
            acc[oo][2] = __builtin_amdgcn_fdot2(W01, q01, acc[oo][2], false);
            acc[oo][2] = __builtin_amdgcn_fdot2(W23, q23, acc[oo][2], false);
            acc[oo][2] = __builtin_amdgcn_fdot2(W4z, q44, acc[oo][2], false);
            acc[oo][3] = __builtin_amdgcn_fdot2(W01, q12, acc[oo][3], false);
            acc[oo][3] = __builtin_amdgcn_fdot2(W23, q34, acc[oo][3], false);
            acc[oo][4] = __builtin_amdgcn_fdot2(W0z, q22, acc[oo][4], false);
            acc[oo][4] = __builtin_amdgcn_fdot2(W12, q34, acc[oo][4], false);
        }
    }
    // convf partial (stride-5 taps = positions 0..4) + atomic combine
    float xf = 0.f;
#pragma unroll
    for (int oo = 0; oo < 8; oo++) {
        const float* wfp = wf + (ob + oo) * 5;
#pragma unroll
        for (int t = 0; t < 5; t++)
            xf = fmaf(wfp[t], fmaxf(acc[oo][t], 0.f), xf);
    }
    if (act) atomicAdd(sc_acc + (size_t)img * DD + d, xf);
}

// ============ k_att: 512 thr, wave per q; Sf tile in LDS ============
__global__ __launch_bounds__(512)
void k_att(const float* __restrict__ Sf, const float* __restrict__ Qf,
           const float* __restrict__ S, const float* __restrict__ Q,
           const float* __restrict__ sc_acc, const float* __restrict__ convf_b,
           float* __restrict__ out) {
    __shared__ float Sft[25][232];
    __shared__ float Ls[8][25];
    const int bid = blockIdx.x, tid = threadIdx.x;
    const int lane = tid & 63, wv = tid >> 6;   // wv 0..7
    const int qg = bid % 25;
    const int nq = (bid / 25) & 3;
    const int b  = bid / 100;
    const int q  = qg * 8 + wv, n0 = nq * 5;
    const float LOG2E = 1.4426950408889634f;
    const float bf0 = convf_b[0];

    const float* sfb = Sf + ((size_t)b * 100 + n0 * 5) * DD;
    for (int e = tid; e < 25 * DD; e += 512) Sft[e / DD][e % DD] = sfb[e];
    __syncthreads();

    // part 1: Ls[wv][idx] = sum_d tanh = 256 - 2*sum rcp(exp2(x)+1)
    float qf[4];
    const float* qfp = Qf + ((size_t)b * NQ + q) * DD;
#pragma unroll
    for (int i = 0; i < 4; i++) {
        int d = lane + 64 * i;
        qf[i] = (d < DD) ? qfp[d] : 0.f;
    }
    for (int idx = 0; idx < 25; idx++) {
        float racc = 0.f;
#pragma unroll
        for (int i = 0; i < 4; i++) {
            int d = lane + 64 * i;
            float s = (d < DD) ? Sft[idx][d] : 0.f;
            float e = __builtin_amdgcn_exp2f(s * qf[i]);
            racc += __builtin_amdgcn_rcpf(e + 1.f);
        }
#pragma unroll
        for (int off = 32; off > 0; off >>= 1) racc += __shfl_xor(racc, off, 64);
        if (lane == 0) Ls[wv][idx] = fmaf(-2.f, racc, 256.f);
    }
    // no barrier: Ls[wv] produced and consumed by the same wave

    // part 2: softmax(K) + einsum + weighted L2
    float qr[4];
    const float* qp = Q + ((size_t)b * NQ + q) * DD;
#pragma unroll
    for (int i = 0; i < 4; i++) {
        int d = lane + 64 * i;
        qr[i] = (d < DD) ? qp[d] : 0.f;
    }
    for (int nl = 0; nl < 5; nl++) {
        const float* lp = Ls[wv] + nl * 5;
        float v0 = lp[0], v1 = lp[1], v2 = lp[2], v3 = lp[3], v4 = lp[4];
        float m = fmaxf(fmaxf(fmaxf(v0, v1), fmaxf(v2, v3)), v4);
        float e0 = __builtin_amdgcn_exp2f((v0 - m) * LOG2E);
        float e1 = __builtin_amdgcn_exp2f((v1 - m) * LOG2E);
        float e2 = __builtin_amdgcn_exp2f((v2 - m) * LOG2E);
        float e3 = __builtin_amdgcn_exp2f((v3 - m) * LOG2E);
        float e4 = __builtin_amdgcn_exp2f((v4 - m) * LOG2E);
        float inv = __builtin_amdgcn_rcpf(e0 + e1 + e2 + e3 + e4);
        float a0 = e0 * inv, a1 = e1 * inv, a2 = e2 * inv, a3 = e3 * inv, a4 = e4 * inv;
        const int n = n0 + nl;
        const float* spn = S + (size_t)(b * NN + n) * KK * DD;
        const float* scp = sc_acc + (size_t)(b * NN + n) * DD;
        float acc = 0.f;
#pragma unroll
        for (int i = 0; i < 4; i++) {
            int d = lane + 64 * i;
            if (d < DD) {
                float rep = a0 * spn[d] + a1 * spn[DD + d] + a2 * spn[2 * DD + d]
                          + a3 * spn[3 * DD + d] + a4 * spn[4 * DD + d];
                float df = rep - qr[i];
                float scw = fmaxf(scp[d] + bf0, 0.f) * 700.f;
                acc = fmaf(df * df, scw, acc);
            }
        }
#pragma unroll
        for (int off = 32; off > 0; off >>= 1) acc += __shfl_xor(acc, off, 64);
        if (lane == 0) out[((size_t)b * NQ + q) * NN + n] = -acc;
    }
}

extern "C" void kernel_launch(void* const* d_in, const int* in_sizes, int n_in,
                              void* d_out, int out_size, void* d_ws, size_t ws_size,
                              hipStream_t stream) {
    const float* S       = (const float*)d_in[0];
    const float* Q       = (const float*)d_in[1];
    const float* fc_w    = (const float*)d_in[2];
    const float* fc_b    = (const float*)d_in[3];
    const float* conv1_w = (const float*)d_in[4];
    const float* conv1_b = (const float*)d_in[5];
    const float* conv2_w = (const float*)d_in[6];
    const float* conv2_b = (const float*)d_in[7];
    const float* convf_w = (const float*)d_in[8];
    const float* convf_b = (const float*)d_in[9];
    float* out = (float*)d_out;

    float* ws = (float*)d_ws;
    float* Wt  = ws;                                    // 52912 dwords
    float* Sf  = Wt + 52912;                            // 184000
    float* Qf  = Sf + 184000;                           // 368000
    float* sc  = Qf + 368000;                           // 36800
    uint4* w2pA = (uint4*)(sc + 36800);                 // 2048 uint4
    uint2* w2pB = (uint2*)((float*)w2pA + 8192);        // 2048 uint2

    (void)hipMemsetAsync(sc, 0, 36800 * sizeof(float), stream);
    k_pre<<<NB_TR + NB_PK + NB_CP, 256, 0, stream>>>(
        fc_w, Wt, conv2_w, w2pA, w2pB, S, out + (size_t)BB * NQ * NN);
    k_main<<<NB_FC + NB_CONV, 256, 0, stream>>>(
        S, Q, conv1_w, conv1_b, w2pA, w2pB, conv2_b, convf_w, sc, Wt, fc_b, Sf, Qf);
    k_att<<<NB_ATT, 512, 0, stream>>>(Sf, Qf, S, Q, sc, convf_b, out);
}

// Round 9
// 79.725 us; speedup vs baseline: 1.5241x; 1.1545x over previous
//
#include <hip/hip_runtime.h>
#include <hip/hip_bf16.h>

typedef _Float16 f16x8 __attribute__((ext_vector_type(8)));
typedef float f32x4 __attribute__((ext_vector_type(4)));

#define BB 8
#define NN 20
#define KK 5
#define DD 230
#define NQ 200

#define NB_TR 207     // transpose 230*230
#define NB_B  200     // build B[2][160][160] f16 + epilogue table
#define NB_CP 180     // 46000 float4 S-copy
#define NB_FC 300     // 2400 rows / 8 per block
#define NB_CONV 1150  // 575 M-blocks x 2 N-halves
#define NB_ATT 800

// ============ k_pre: fc_w transpose + im2col B build + S passthrough ============
__global__ void k_pre(const float* __restrict__ fc_w, float* __restrict__ Wt,
                      const float* __restrict__ w2, const float* __restrict__ b2,
                      const float* __restrict__ wf,
                      _Float16* __restrict__ Bglob, float2* __restrict__ tblg,
                      const float* __restrict__ S, float* __restrict__ Scopy) {
    const int bid = blockIdx.x, tid = threadIdx.x;
    if (bid < NB_TR) {
        int idx = bid * 256 + tid;
        if (idx < DD * DD) {
            int i = idx / DD, j = idx % DD;
            Wt[j * DD + i] = fc_w[idx];
        }
    } else if (bid < NB_TR + NB_B) {
        int g = (bid - NB_TR) * 256 + tid;   // 0..51199
        if (g < 51200) {
            int hn = g / 160, k = g - hn * 160;
            int h = hn / 160, n = hn - h * 160;
            int o = h * 32 + n / 5, i = n % 5;
            int c = k / 5, j = k - c * 5;
            int t = j - i + 2;
            float val = (t >= 0 && t < 5) ? w2[(o * 32 + c) * 5 + t] : 0.f;
            Bglob[g] = (_Float16)val;
            if (g < 320) {
                int h2 = g / 160, nn = g - h2 * 160;
                int o2 = h2 * 32 + nn / 5, i2 = nn % 5;
                tblg[g] = make_float2(b2[o2], wf[o2 * 5 + i2]);
            }
        }
    } else {
        int g = (bid - NB_TR - NB_B) * 256 + tid;
        if (g < 46000) ((float4*)Scopy)[g] = ((const float4*)S)[g];
    }
}

// ============ k_main: fc (blocks 0..299) + conv-as-MFMA (blocks 300..1449) ============
__global__ __launch_bounds__(256, 2)
void k_main(const float* __restrict__ S, const float* __restrict__ Q,
            const float* __restrict__ w1, const float* __restrict__ b1,
            const _Float16* __restrict__ Bglob, const float2* __restrict__ tblg,
            float* __restrict__ sc_acc,
            const float* __restrict__ Wt, const float* __restrict__ fc_b,
            float* __restrict__ Sf, float* __restrict__ Qf) {
    __shared__ __align__(16) _Float16 Bs[160 * 168];   // 53760 B
    __shared__ __align__(16) _Float16 Xs[64 * 168];    // 21504 B
    __shared__ float2 Tb[160];                         //  1280 B
    const int bid = blockIdx.x, tid = threadIdx.x;

    if (bid < NB_FC) {
        // ---- fc: 8 rows per block ----
        const int r0 = bid * 8;
        const float* in;
        float* out;
        float scale;
        if (r0 < BB * NN * KK) {
            in = S + (size_t)r0 * DD;
            out = Sf + (size_t)r0 * DD;
            scale = 2.8853900817779268f;   // 2*log2(e)
        } else {
            int r = r0 - BB * NN * KK;
            in = Q + (size_t)r * DD;
            out = Qf + (size_t)r * DD;
            scale = 1.0f;
        }
        const int c = tid;
        const int cc = c < DD ? c : DD - 1;
        float a[8] = {0.f, 0.f, 0.f, 0.f, 0.f, 0.f, 0.f, 0.f};
        for (int k = 0; k < DD; k++) {
            float w = Wt[k * DD + cc];
#pragma unroll
            for (int r = 0; r < 8; r++) a[r] = fmaf(in[r * DD + k], w, a[r]);
        }
        if (c < DD) {
            float bb = fc_b[c];
#pragma unroll
            for (int r = 0; r < 8; r++) out[r * DD + c] = (a[r] + bb) * scale;
        }
        return;
    }

    // ---- conv: M-tile = 64 rows of (img,d), N-half = 160 cols of (o,i) ----
    const int bid2 = bid - NB_FC;
    const int Mb = bid2 >> 1;
    const int h  = bid2 & 1;
    const int lane = tid & 63;
    const int wv = __builtin_amdgcn_readfirstlane(tid >> 6);  // 0..3

    // stage B half (160x160 f16 -> padded 168/row), load-all then write-all
    const uint4* gB = (const uint4*)Bglob + h * 3200;
    uint4 tmp[13];
#pragma unroll
    for (int it = 0; it < 13; ++it) {
        int idx = tid + 256 * it;
        tmp[it] = (idx < 3200) ? gB[idx] : make_uint4(0, 0, 0, 0);
    }
    if (tid < 160) Tb[tid] = tblg[h * 160 + tid];
#pragma unroll
    for (int it = 0; it < 13; ++it) {
        int idx = tid + 256 * it;
        if (idx < 3200) {
            int rowb = idx / 20, cq = idx - rowb * 20;
            *(uint4*)&Bs[rowb * 168 + cq * 8] = tmp[it];
        }
    }

    // conv1 for 64 rows; thread = (row = tid&63, c-group = tid>>6 covering 8 c)
    {
        const int row = tid & 63;
        const int m = Mb * 64 + row;
        const int img = m / DD;
        const int d = m - img * DD;
        const float* sp = S + (size_t)img * KK * DD + d;
        float in5[5];
#pragma unroll
        for (int j = 0; j < 5; j++) in5[j] = sp[j * DD];
#pragma unroll
        for (int ccc = 0; ccc < 8; ccc++) {
            int c = wv * 8 + ccc;
            float wl[5];
#pragma unroll
            for (int t = 0; t < 5; t++) wl[t] = w1[c * 5 + t];
            float bb = b1[c];
#pragma unroll
            for (int i = 0; i < 5; i++) {
                float a = bb;
#pragma unroll
                for (int t = 0; t < 5; t++) {
                    int j = i + t - 2;
                    if (j >= 0 && j < 5) a = fmaf(wl[t], in5[j], a);
                }
                Xs[row * 168 + c * 5 + i] = (_Float16)fmaxf(a, 0.f);
            }
        }
    }
    __syncthreads();

    // MFMA: wave wv owns M-strip [wv*16, wv*16+16), full N-half (10 tiles), K=160
    const int arow = wv * 16 + (lane & 15);
    const int kg8 = (lane >> 4) * 8;
    const int ncl = lane & 15;
    f16x8 af[5];
#pragma unroll
    for (int ks = 0; ks < 5; ks++)
        af[ks] = *(const f16x8*)&Xs[arow * 168 + ks * 32 + kg8];
    f32x4 acc[10];
#pragma unroll
    for (int nt = 0; nt < 10; nt++) {
        f32x4 a = {0.f, 0.f, 0.f, 0.f};
#pragma unroll
        for (int ks = 0; ks < 5; ks++) {
            f16x8 bf = *(const f16x8*)&Bs[(nt * 16 + ncl) * 168 + ks * 32 + kg8];
            a = __builtin_amdgcn_mfma_f32_16x16x32_f16(af[ks], bf, a, 0, 0, 0);
        }
        acc[nt] = a;
    }

    // epilogue: relu(C + b2[o]) * wf[o][i], sum over this half's 160 (o,i)
    float xf[4] = {0.f, 0.f, 0.f, 0.f};
#pragma unroll
    for (int nt = 0; nt < 10; nt++) {
        float2 bw = Tb[nt * 16 + ncl];
#pragma unroll
        for (int r = 0; r < 4; r++)
            xf[r] = fmaf(fmaxf(acc[nt][r] + bw.x, 0.f), bw.y, xf[r]);
    }
#pragma unroll
    for (int off = 1; off < 16; off <<= 1) {
#pragma unroll
        for (int r = 0; r < 4; r++) xf[r] += __shfl_xor(xf[r], off, 64);
    }
    if ((lane & 15) == 0) {
        int mbase = Mb * 64 + wv * 16 + (lane >> 4) * 4;
#pragma unroll
        for (int r = 0; r < 4; r++)
            atomicAdd(sc_acc + mbase + r, xf[r]);
    }
}

// ============ k_att: 512 thr, wave per q; Sf tile in LDS ============
__global__ __launch_bounds__(512)
void k_att(const float* __restrict__ Sf, const float* __restrict__ Qf,
           const float* __restrict__ S, const float* __restrict__ Q,
           const float* __restrict__ sc_acc, const float* __restrict__ convf_b,
           float* __restrict__ out) {
    __shared__ float Sft[25][232];
    __shared__ float Ls[8][25];
    const int bid = blockIdx.x, tid = threadIdx.x;
    const int lane = tid & 63, wv = tid >> 6;   // wv 0..7
    const int qg = bid % 25;
    const int nq = (bid / 25) & 3;
    const int b  = bid / 100;
    const int q  = qg * 8 + wv, n0 = nq * 5;
    const float LOG2E = 1.4426950408889634f;
    const float bf0 = convf_b[0];

    const float* sfb = Sf + ((size_t)b * 100 + n0 * 5) * DD;
    for (int e = tid; e < 25 * DD; e += 512) Sft[e / DD][e % DD] = sfb[e];
    __syncthreads();

    float qf[4];
    const float* qfp = Qf + ((size_t)b * NQ + q) * DD;
#pragma unroll
    for (int i = 0; i < 4; i++) {
        int d = lane + 64 * i;
        qf[i] = (d < DD) ? qfp[d] : 0.f;
    }
    for (int idx = 0; idx < 25; idx++) {
        float racc = 0.f;
#pragma unroll
        for (int i = 0; i < 4; i++) {
            int d = lane + 64 * i;
            float s = (d < DD) ? Sft[idx][d] : 0.f;
            float e = __builtin_amdgcn_exp2f(s * qf[i]);
            racc += __builtin_amdgcn_rcpf(e + 1.f);
        }
#pragma unroll
        for (int off = 32; off > 0; off >>= 1) racc += __shfl_xor(racc, off, 64);
        if (lane == 0) Ls[wv][idx] = fmaf(-2.f, racc, 256.f);
    }

    float qr[4];
    const float* qp = Q + ((size_t)b * NQ + q) * DD;
#pragma unroll
    for (int i = 0; i < 4; i++) {
        int d = lane + 64 * i;
        qr[i] = (d < DD) ? qp[d] : 0.f;
    }
    for (int nl = 0; nl < 5; nl++) {
        const float* lp = Ls[wv] + nl * 5;
        float v0 = lp[0], v1 = lp[1], v2 = lp[2], v3 = lp[3], v4 = lp[4];
        float m = fmaxf(fmaxf(fmaxf(v0, v1), fmaxf(v2, v3)), v4);
        float e0 = __builtin_amdgcn_exp2f((v0 - m) * LOG2E);
        float e1 = __builtin_amdgcn_exp2f((v1 - m) * LOG2E);
        float e2 = __builtin_amdgcn_exp2f((v2 - m) * LOG2E);
        float e3 = __builtin_amdgcn_exp2f((v3 - m) * LOG2E);
        float e4 = __builtin_amdgcn_exp2f((v4 - m) * LOG2E);
        float inv = __builtin_amdgcn_rcpf(e0 + e1 + e2 + e3 + e4);
        float a0 = e0 * inv, a1 = e1 * inv, a2 = e2 * inv, a3 = e3 * inv, a4 = e4 * inv;
        const int n = n0 + nl;
        const float* spn = S + (size_t)(b * NN + n) * KK * DD;
        const float* scp = sc_acc + (size_t)(b * NN + n) * DD;
        float acc = 0.f;
#pragma unroll
        for (int i = 0; i < 4; i++) {
            int d = lane + 64 * i;
            if (d < DD) {
                float rep = a0 * spn[d] + a1 * spn[DD + d] + a2 * spn[2 * DD + d]
                          + a3 * spn[3 * DD + d] + a4 * spn[4 * DD + d];
                float df = rep - qr[i];
                float scw = fmaxf(scp[d] + bf0, 0.f) * 700.f;
                acc = fmaf(df * df, scw, acc);
            }
        }
#pragma unroll
        for (int off = 32; off > 0; off >>= 1) acc += __shfl_xor(acc, off, 64);
        if (lane == 0) out[((size_t)b * NQ + q) * NN + n] = -acc;
    }
}

extern "C" void kernel_launch(void* const* d_in, const int* in_sizes, int n_in,
                              void* d_out, int out_size, void* d_ws, size_t ws_size,
                              hipStream_t stream) {
    const float* S       = (const float*)d_in[0];
    const float* Q       = (const float*)d_in[1];
    const float* fc_w    = (const float*)d_in[2];
    const float* fc_b    = (const float*)d_in[3];
    const float* conv1_w = (const float*)d_in[4];
    const float* conv1_b = (const float*)d_in[5];
    const float* conv2_w = (const float*)d_in[6];
    const float* conv2_b = (const float*)d_in[7];
    const float* convf_w = (const float*)d_in[8];
    const float* convf_b = (const float*)d_in[9];
    float* out = (float*)d_out;

    float* ws = (float*)d_ws;
    float* Wt  = ws;                                   // 52912 dwords
    float* Sf  = Wt + 52912;                           // 184000
    float* Qf  = Sf + 184000;                          // 368000
    float* sc  = Qf + 368000;                          // 36800
    _Float16* Bglob = (_Float16*)(sc + 36800);         // 25600 dwords
    float2* tblg = (float2*)(sc + 36800 + 25600);      // 640 dwords

    (void)hipMemsetAsync(sc, 0, 36800 * sizeof(float), stream);
    k_pre<<<NB_TR + NB_B + NB_CP, 256, 0, stream>>>(
        fc_w, Wt, conv2_w, conv2_b, convf_w, Bglob, tblg,
        S, out + (size_t)BB * NQ * NN);
    k_main<<<NB_FC + NB_CONV, 256, 0, stream>>>(
        S, Q, conv1_w, conv1_b, Bglob, tblg, sc, Wt, fc_b, Sf, Qf);
    k_att<<<NB_ATT, 512, 0, stream>>>(Sf, Qf, S, Q, sc, convf_b, out);
}

// Round 10
// 78.124 us; speedup vs baseline: 1.5553x; 1.0205x over previous
//
#include <hip/hip_runtime.h>
#include <hip/hip_bf16.h>

typedef _Float16 f16x8 __attribute__((ext_vector_type(8)));
typedef float f32x4 __attribute__((ext_vector_type(4)));

#define BB 8
#define NN 20
#define KK 5
#define DD 230
#define NQ 200

#define NB_TR 207     // transpose 230x230 -> Wt[230][232]
#define NB_B  200     // build B[2][160][160] f16 + epilogue table
#define NB_CONV 1150  // 575 M-blocks x 2 N-halves
#define NB_FC 600     // 2400 rows / 4 per block
#define NB_ATT 800
#define NB_CP 90      // 46000 float4 / 512

// ============ k_pre: fc_w transpose (padded) + im2col B build ============
__global__ void k_pre(const float* __restrict__ fc_w, float* __restrict__ Wt,
                      const float* __restrict__ w2, const float* __restrict__ b2,
                      const float* __restrict__ wf,
                      _Float16* __restrict__ Bglob, float2* __restrict__ tblg) {
    const int bid = blockIdx.x, tid = threadIdx.x;
    if (bid < NB_TR) {
        int idx = bid * 256 + tid;
        if (idx < DD * DD) {
            int i = idx / DD, j = idx - (idx / DD) * DD;
            Wt[j * 232 + i] = fc_w[idx];
        }
    } else {
        int g = (bid - NB_TR) * 256 + tid;   // < 51200 exactly
        int hn = g / 160, k = g - hn * 160;
        int h = hn / 160, n = hn - h * 160;
        int o = h * 32 + n / 5, i = n % 5;
        int c = k / 5, j = k - c * 5;
        int t = j - i + 2;
        float val = (t >= 0 && t < 5) ? w2[(o * 32 + c) * 5 + t] : 0.f;
        Bglob[g] = (_Float16)val;
        if (g < 320) {
            int h2 = g / 160, nn = g - h2 * 160;
            int o2 = h2 * 32 + nn / 5, i2 = nn % 5;
            tblg[g] = make_float2(b2[o2], wf[o2 * 5 + i2]);
        }
    }
}

// ============ k_main: conv-as-MFMA (blocks 0..1149) + fc (1150..1749) ============
__global__ __launch_bounds__(256, 2)
void k_main(const float* __restrict__ S, const float* __restrict__ Q,
            const float* __restrict__ w1, const float* __restrict__ b1,
            const _Float16* __restrict__ Bglob, const float2* __restrict__ tblg,
            float* __restrict__ scp,
            const float* __restrict__ Wt, const float* __restrict__ fc_b,
            float* __restrict__ Sf, float* __restrict__ Qf) {
    __shared__ __align__(16) _Float16 Bs[160 * 168];   // 53760 B
    __shared__ __align__(16) _Float16 Xs[64 * 168];    // 21504 B
    __shared__ float2 Tb[160];
    const int bid = blockIdx.x, tid = threadIdx.x;

    if (bid >= NB_CONV) {
        // ---- fc: 4 rows per block, thread = (row = tid>>6, cols = 4*(tid&63)) ----
        const int fb = bid - NB_CONV;
        const int lane = tid & 63;
        const int row = __builtin_amdgcn_readfirstlane(fb * 4 + (tid >> 6));
        const float* inp;
        float* outp;
        float scale;
        if (row < BB * NN * KK) {
            inp = S + (size_t)row * DD;
            outp = Sf + (size_t)row * DD;
            scale = 2.8853900817779268f;   // 2*log2(e)
        } else {
            int r = row - BB * NN * KK;
            inp = Q + (size_t)r * DD;
            outp = Qf + (size_t)r * DD;
            scale = 1.0f;
        }
        const int c0 = lane * 4;
        float a0 = 0.f, a1 = 0.f, a2 = 0.f, a3 = 0.f;
#pragma unroll 5
        for (int k = 0; k < DD; k++) {
            float4 w = *(const float4*)&Wt[k * 232 + c0];
            float s = inp[k];
            a0 = fmaf(s, w.x, a0);
            a1 = fmaf(s, w.y, a1);
            a2 = fmaf(s, w.z, a2);
            a3 = fmaf(s, w.w, a3);
        }
        float av[4] = {a0, a1, a2, a3};
#pragma unroll
        for (int j = 0; j < 4; j++) {
            int c = c0 + j;
            if (c < DD) outp[c] = (av[j] + fc_b[c]) * scale;
        }
        return;
    }

    // ---- conv: M-tile = 64 rows of (img,d), N-half = 160 cols of (o,i) ----
    const int Mb = bid >> 1;
    const int h  = bid & 1;
    const int lane = tid & 63;
    const int wv = __builtin_amdgcn_readfirstlane(tid >> 6);  // 0..3

    // stage B half (160x160 f16 -> padded 168/row)
    const uint4* gB = (const uint4*)Bglob + h * 3200;
    uint4 tmp[13];
#pragma unroll
    for (int it = 0; it < 13; ++it) {
        int idx = tid + 256 * it;
        tmp[it] = (idx < 3200) ? gB[idx] : make_uint4(0, 0, 0, 0);
    }
    if (tid < 160) Tb[tid] = tblg[h * 160 + tid];
#pragma unroll
    for (int it = 0; it < 13; ++it) {
        int idx = tid + 256 * it;
        if (idx < 3200) {
            int rowb = idx / 20, cq = idx - rowb * 20;
            *(uint4*)&Bs[rowb * 168 + cq * 8] = tmp[it];
        }
    }

    // conv1 for 64 rows; thread = (row = tid&63, c-group = wv covering 8 c)
    {
        const int row = tid & 63;
        const int m = Mb * 64 + row;
        const int img = m / DD;
        const int d = m - img * DD;
        const float* sp = S + (size_t)img * KK * DD + d;
        float in5[5];
#pragma unroll
        for (int j = 0; j < 5; j++) in5[j] = sp[j * DD];
#pragma unroll
        for (int ccc = 0; ccc < 8; ccc++) {
            int c = wv * 8 + ccc;
            float wl[5];
#pragma unroll
            for (int t = 0; t < 5; t++) wl[t] = w1[c * 5 + t];
            float bb = b1[c];
#pragma unroll
            for (int i = 0; i < 5; i++) {
                float a = bb;
#pragma unroll
                for (int t = 0; t < 5; t++) {
                    int j = i + t - 2;
                    if (j >= 0 && j < 5) a = fmaf(wl[t], in5[j], a);
                }
                Xs[row * 168 + c * 5 + i] = (_Float16)fmaxf(a, 0.f);
            }
        }
    }
    __syncthreads();

    // MFMA: wave wv owns M-strip [wv*16, wv*16+16), full N-half (10 tiles), K=160
    const int arow = wv * 16 + (lane & 15);
    const int kg8 = (lane >> 4) * 8;
    const int ncl = lane & 15;
    f16x8 af[5];
#pragma unroll
    for (int ks = 0; ks < 5; ks++)
        af[ks] = *(const f16x8*)&Xs[arow * 168 + ks * 32 + kg8];
    f32x4 acc[10];
#pragma unroll
    for (int nt = 0; nt < 10; nt++) {
        f32x4 a = {0.f, 0.f, 0.f, 0.f};
#pragma unroll
        for (int ks = 0; ks < 5; ks++) {
            f16x8 bf = *(const f16x8*)&Bs[(nt * 16 + ncl) * 168 + ks * 32 + kg8];
            a = __builtin_amdgcn_mfma_f32_16x16x32_f16(af[ks], bf, a, 0, 0, 0);
        }
        acc[nt] = a;
    }

    // epilogue: relu(C + b2[o]) * wf[o][i], sum over this half's 160 (o,i)
    float xf[4] = {0.f, 0.f, 0.f, 0.f};
#pragma unroll
    for (int nt = 0; nt < 10; nt++) {
        float2 bw = Tb[nt * 16 + ncl];
#pragma unroll
        for (int r = 0; r < 4; r++)
            xf[r] = fmaf(fmaxf(acc[nt][r] + bw.x, 0.f), bw.y, xf[r]);
    }
#pragma unroll
    for (int off = 1; off < 16; off <<= 1) {
#pragma unroll
        for (int r = 0; r < 4; r++) xf[r] += __shfl_xor(xf[r], off, 64);
    }
    if ((lane & 15) == 0) {
        int mbase = Mb * 64 + wv * 16 + (lane >> 4) * 4;
#pragma unroll
        for (int r = 0; r < 4; r++)
            scp[h * 36800 + mbase + r] = xf[r];    // exclusive rows: no atomic
    }
}

// ============ k_att: att (blocks 0..799) + S-copy (800..889); 512 thr ============
__global__ __launch_bounds__(512)
void k_att(const float* __restrict__ Sf, const float* __restrict__ Qf,
           const float* __restrict__ S, const float* __restrict__ Q,
           const float* __restrict__ scp, const float* __restrict__ convf_b,
           float* __restrict__ out, float* __restrict__ Scopy) {
    __shared__ float Sft[25][232];
    __shared__ float Ls[8][25];
    const int bid = blockIdx.x, tid = threadIdx.x;
    if (bid >= NB_ATT) {
        int g = (bid - NB_ATT) * 512 + tid;
        if (g < 46000) ((float4*)Scopy)[g] = ((const float4*)S)[g];
        return;
    }
    const int lane = tid & 63, wv = tid >> 6;   // wv 0..7
    const int qg = bid % 25;
    const int nq = (bid / 25) & 3;
    const int b  = bid / 100;
    const int q  = qg * 8 + wv, n0 = nq * 5;
    const float LOG2E = 1.4426950408889634f;
    const float bf0 = convf_b[0];

    const float* sfb = Sf + ((size_t)b * 100 + n0 * 5) * DD;
    for (int e = tid; e < 25 * DD; e += 512) Sft[e / DD][e % DD] = sfb[e];
    __syncthreads();

    float qf[4];
    const float* qfp = Qf + ((size_t)b * NQ + q) * DD;
#pragma unroll
    for (int i = 0; i < 4; i++) {
        int d = lane + 64 * i;
        qf[i] = (d < DD) ? qfp[d] : 0.f;
    }
    for (int idx = 0; idx < 25; idx++) {
        float racc = 0.f;
#pragma unroll
        for (int i = 0; i < 4; i++) {
            int d = lane + 64 * i;
            float s = (d < DD) ? Sft[idx][d] : 0.f;
            float e = __builtin_amdgcn_exp2f(s * qf[i]);
            racc += __builtin_amdgcn_rcpf(e + 1.f);
        }
#pragma unroll
        for (int off = 32; off > 0; off >>= 1) racc += __shfl_xor(racc, off, 64);
        if (lane == 0) Ls[wv][idx] = fmaf(-2.f, racc, 256.f);
    }

    float qr[4];
    const float* qp = Q + ((size_t)b * NQ + q) * DD;
#pragma unroll
    for (int i = 0; i < 4; i++) {
        int d = lane + 64 * i;
        qr[i] = (d < DD) ? qp[d] : 0.f;
    }
    for (int nl = 0; nl < 5; nl++) {
        const float* lp = Ls[wv] + nl * 5;
        float v0 = lp[0], v1 = lp[1], v2 = lp[2], v3 = lp[3], v4 = lp[4];
        float m = fmaxf(fmaxf(fmaxf(v0, v1), fmaxf(v2, v3)), v4);
        float e0 = __builtin_amdgcn_exp2f((v0 - m) * LOG2E);
        float e1 = __builtin_amdgcn_exp2f((v1 - m) * LOG2E);
        float e2 = __builtin_amdgcn_exp2f((v2 - m) * LOG2E);
        float e3 = __builtin_amdgcn_exp2f((v3 - m) * LOG2E);
        float e4 = __builtin_amdgcn_exp2f((v4 - m) * LOG2E);
        float inv = __builtin_amdgcn_rcpf(e0 + e1 + e2 + e3 + e4);
        float a0 = e0 * inv, a1 = e1 * inv, a2 = e2 * inv, a3 = e3 * inv, a4 = e4 * inv;
        const int n = n0 + nl;
        const float* spn = S + (size_t)(b * NN + n) * KK * DD;
        const float* s0 = scp + (size_t)(b * NN + n) * DD;   // half0; half1 at +36800
        float acc = 0.f;
#pragma unroll
        for (int i = 0; i < 4; i++) {
            int d = lane + 64 * i;
            if (d < DD) {
                float rep = a0 * spn[d] + a1 * spn[DD + d] + a2 * spn[2 * DD + d]
                          + a3 * spn[3 * DD + d] + a4 * spn[4 * DD + d];
                float df = rep - qr[i];
                float scw = fmaxf(s0[d] + s0[36800 + d] + bf0, 0.f) * 700.f;
                acc = fmaf(df * df, scw, acc);
            }
        }
#pragma unroll
        for (int off = 32; off > 0; off >>= 1) acc += __shfl_xor(acc, off, 64);
        if (lane == 0) out[((size_t)b * NQ + q) * NN + n] = -acc;
    }
}

extern "C" void kernel_launch(void* const* d_in, const int* in_sizes, int n_in,
                              void* d_out, int out_size, void* d_ws, size_t ws_size,
                              hipStream_t stream) {
    const float* S       = (const float*)d_in[0];
    const float* Q       = (const float*)d_in[1];
    const float* fc_w    = (const float*)d_in[2];
    const float* fc_b    = (const float*)d_in[3];
    const float* conv1_w = (const float*)d_in[4];
    const float* conv1_b = (const float*)d_in[5];
    const float* conv2_w = (const float*)d_in[6];
    const float* conv2_b = (const float*)d_in[7];
    const float* convf_w = (const float*)d_in[8];
    const float* convf_b = (const float*)d_in[9];
    float* out = (float*)d_out;

    float* ws = (float*)d_ws;
    float* Wt  = ws;                                   // 232*232 = 53824 dwords
    float* Sf  = Wt + 53824;                           // 184000
    float* Qf  = Sf + 184000;                          // 368000
    float* scp = Qf + 368000;                          // 73600 (2 halves)
    _Float16* Bglob = (_Float16*)(scp + 73600);        // 25600 dwords
    float2* tblg = (float2*)(scp + 73600 + 25600);     // 640 dwords

    k_pre<<<NB_TR + NB_B, 256, 0, stream>>>(
        fc_w, Wt, conv2_w, conv2_b, convf_w, Bglob, tblg);
    k_main<<<NB_CONV + NB_FC, 256, 0, stream>>>(
        S, Q, conv1_w, conv1_b, Bglob, tblg, scp, Wt, fc_b, Sf, Qf);
    k_att<<<NB_ATT + NB_CP, 512, 0, stream>>>(
        Sf, Qf, S, Q, scp, convf_b, out, out + (size_t)BB * NQ * NN);
}